// Round 6
// baseline (171.784 us; speedup 1.0000x reference)
//
#include <hip/hip_runtime.h>
#include <hip/hip_bf16.h>

// WaveletLinear: y[b,o] = sum_i w[o,i] * (1 - s^2) * exp(-0.5 s^2),
//   s = (x[b,i] - t[o,i]) / (A_MIN + softplus(sr[o,i]) + EPS)
// u = K*s^2, K = 0.5*log2(e); e = exp2(-u); y = sum w*e - (1/K) sum w*(u*e).
//
// R6: measured busy/wave-step ~150 cyc (R4+R5 agree): 40 f32 slots x 2 +
// 8 v_exp x 8 — packed f32 gains nothing on CDNA4, exp blocks issue 8 cyc.
// Busy floor ~32 us; R5's 54 us = 40% exposed latency at 16 waves/CU.
// Fix: b-tile 8 -> 16 KB LDS -> 4 blocks/CU x 8 waves = 8 waves/SIMD.
// Wave = all 8 b x i-eighth(64). XCD-decoded block id: 2 o-slabs per XCD L2,
// co-resident blocks share o-slab for L1 param reuse.

#define WL_A_MIN 0.001f
#define WL_EPS   1e-8f

constexpr int WL_B = 512;
constexpr int WL_O = 1024;
constexpr int WL_I = 512;

#define WL_SQK  0.84932180553704583800f   // sqrt(0.5*log2 e)
#define WL_IK   1.38629436111989061883f   // 1/K = 2 ln 2
#define WL_L2E  1.44269504088896340736f
#define WL_LN2  0.69314718055994530942f

typedef float v2f __attribute__((ext_vector_type(2)));

struct P3 { float nti, inv, w; };          // 12 B

__device__ __forceinline__ float fast_exp2(float a) {
#if __has_builtin(__builtin_amdgcn_exp2f)
    return __builtin_amdgcn_exp2f(a);
#else
    return exp2f(a);
#endif
}
__device__ __forceinline__ float fast_log2(float a) {
#if __has_builtin(__builtin_amdgcn_logf)
    return __builtin_amdgcn_logf(a);
#else
    return __log2f(a);
#endif
}
__device__ __forceinline__ float fast_rcp(float a) {
#if __has_builtin(__builtin_amdgcn_rcpf)
    return __builtin_amdgcn_rcpf(a);
#else
    return 1.0f / a;
#endif
}

__global__ __launch_bounds__(256) void wl_prep(
    const float* __restrict__ translation,
    const float* __restrict__ scale_raw,
    const float* __restrict__ weights,
    P3* __restrict__ pT3)
{
    const int lane   = threadIdx.x & 63;
    const int ic     = threadIdx.x >> 6;               // 0..3
    const int o      = blockIdx.x * 64 + lane;
    const int i_base = blockIdx.y * 64 + ic * 16;

    #pragma unroll 4
    for (int k = 0; k < 16; ++k) {
        int i  = i_base + k;
        int gi = o * WL_I + i;
        float t  = translation[gi];
        float sr = scale_raw[gi];
        float w  = weights[gi];
        float ex    = fast_exp2(sr * WL_L2E);          // softplus via hw exp2/log2
        float sp    = fast_log2(1.0f + ex) * WL_LN2;
        float inv   = fast_rcp(WL_A_MIN + sp + WL_EPS);
        float inv_s = inv * WL_SQK;
        P3 pv; pv.nti = -t * inv_s; pv.inv = inv_s; pv.w = w;
        pT3[(size_t)i * WL_O + o] = pv;
    }
}

// 1024 blocks x 512 thr (8 waves). bid decode: xcd = bid&7, slot = bid>>3,
// o_slab = xcd*2 + (slot&1)  (each XCD L2 caches 2 param slabs, 786 KB),
// b_tile = slot>>1. Co-resident CU blocks (bid +- 256k) share o_slab -> L1.
__global__ __launch_bounds__(512, 8) void wl_main(
    const float* __restrict__ x,
    const P3* __restrict__ pT3,
    float* __restrict__ out)
{
    __shared__ float smem[WL_I * 8];                   // 16 KB: xT[i][b_l]

    const int tid  = threadIdx.x;
    const int lane = tid & 63;
    const int wid  = tid >> 6;                         // 0..7 = i-eighth
    const int bid  = blockIdx.x;
    const int xcd  = bid & 7;
    const int slot = bid >> 3;
    const int o    = (xcd * 2 + (slot & 1)) * 64 + lane;
    const int b0   = (slot >> 1) * 8;

    // ---- stage x^T once: xT[i*8 + b_l] ----
    {
        const int b_l = tid & 7;
        const int seg = tid >> 3;                      // 0..63 -> i = seg*8..+8
        const float* xg = &x[(b0 + b_l) * WL_I + seg * 8];
        float4 v0 = *reinterpret_cast<const float4*>(xg);
        float4 v1 = *reinterpret_cast<const float4*>(xg + 4);
        int a0 = (seg * 8) * 8 + b_l;
        smem[a0 + 0 * 8] = v0.x;
        smem[a0 + 1 * 8] = v0.y;
        smem[a0 + 2 * 8] = v0.z;
        smem[a0 + 3 * 8] = v0.w;
        smem[a0 + 4 * 8] = v1.x;
        smem[a0 + 5 * 8] = v1.y;
        smem[a0 + 6 * 8] = v1.z;
        smem[a0 + 7 * 8] = v1.w;
    }
    __syncthreads();

    const P3* pp = pT3 + o;

    v2f aE0 = {0.f,0.f}, aE1 = {0.f,0.f}, aE2 = {0.f,0.f}, aE3 = {0.f,0.f};
    v2f aU0 = {0.f,0.f}, aU1 = {0.f,0.f}, aU2 = {0.f,0.f}, aU3 = {0.f,0.f};

    const int iBeg = wid * 64;
    #pragma unroll 8
    for (int ii = 0; ii < 64; ++ii) {
        const int i = iBeg + ii;
        P3 p = pp[(size_t)i * WL_O];                   // 768B/wave coalesced
        float4 xa = *reinterpret_cast<const float4*>(&smem[i * 8]);      // uniform
        float4 xb = *reinterpret_cast<const float4*>(&smem[i * 8 + 4]);  // uniform

        v2f nti = {p.nti, p.nti};
        v2f inv = {p.inv, p.inv};
        v2f wv  = {p.w,  p.w};

        v2f x01 = {xa.x, xa.y};
        v2f x23 = {xa.z, xa.w};
        v2f x45 = {xb.x, xb.y};
        v2f x67 = {xb.z, xb.w};

        v2f s0 = __builtin_elementwise_fma(x01, inv, nti);
        v2f s1 = __builtin_elementwise_fma(x23, inv, nti);
        v2f s2 = __builtin_elementwise_fma(x45, inv, nti);
        v2f s3 = __builtin_elementwise_fma(x67, inv, nti);
        v2f u0 = s0 * s0;
        v2f u1 = s1 * s1;
        v2f u2 = s2 * s2;
        v2f u3 = s3 * s3;
        v2f e0 = {fast_exp2(-u0.x), fast_exp2(-u0.y)};
        v2f e1 = {fast_exp2(-u1.x), fast_exp2(-u1.y)};
        v2f e2 = {fast_exp2(-u2.x), fast_exp2(-u2.y)};
        v2f e3 = {fast_exp2(-u3.x), fast_exp2(-u3.y)};
        aE0 = __builtin_elementwise_fma(wv, e0, aE0);
        aE1 = __builtin_elementwise_fma(wv, e1, aE1);
        aE2 = __builtin_elementwise_fma(wv, e2, aE2);
        aE3 = __builtin_elementwise_fma(wv, e3, aE3);
        v2f ue0 = u0 * e0;
        v2f ue1 = u1 * e1;
        v2f ue2 = u2 * e2;
        v2f ue3 = u3 * e3;
        aU0 = __builtin_elementwise_fma(wv, ue0, aU0);
        aU1 = __builtin_elementwise_fma(wv, ue1, aU1);
        aU2 = __builtin_elementwise_fma(wv, ue2, aU2);
        aU3 = __builtin_elementwise_fma(wv, ue3, aU3);
    }

    // ---- pairwise tree reduction over the 8 i-eighths (reuse 16 KB smem) ----
    float E[8] = {aE0.x, aE0.y, aE1.x, aE1.y, aE2.x, aE2.y, aE3.x, aE3.y};
    float U[8] = {aU0.x, aU0.y, aU1.x, aU1.y, aU2.x, aU2.y, aU3.x, aU3.y};

    __syncthreads();                                   // done reading xT
    float4* s4 = reinterpret_cast<float4*>(smem);
    // Round A: waves 4..7 dump (4096 floats), waves 0..3 add.
    if (wid >= 4) {
        float4* d = &s4[((wid - 4) * 64 + lane) * 4];
        d[0] = make_float4(E[0], E[1], E[2], E[3]);
        d[1] = make_float4(E[4], E[5], E[6], E[7]);
        d[2] = make_float4(U[0], U[1], U[2], U[3]);
        d[3] = make_float4(U[4], U[5], U[6], U[7]);
    }
    __syncthreads();
    if (wid < 4) {
        const float4* sv = &s4[(wid * 64 + lane) * 4];
        float4 a = sv[0], b = sv[1], c = sv[2], d = sv[3];
        E[0] += a.x; E[1] += a.y; E[2] += a.z; E[3] += a.w;
        E[4] += b.x; E[5] += b.y; E[6] += b.z; E[7] += b.w;
        U[0] += c.x; U[1] += c.y; U[2] += c.z; U[3] += c.w;
        U[4] += d.x; U[5] += d.y; U[6] += d.z; U[7] += d.w;
    }
    __syncthreads();
    // Round B: waves 2,3 dump, waves 0,1 add.
    if (wid == 2 || wid == 3) {
        float4* d = &s4[((wid - 2) * 64 + lane) * 4];
        d[0] = make_float4(E[0], E[1], E[2], E[3]);
        d[1] = make_float4(E[4], E[5], E[6], E[7]);
        d[2] = make_float4(U[0], U[1], U[2], U[3]);
        d[3] = make_float4(U[4], U[5], U[6], U[7]);
    }
    __syncthreads();
    if (wid < 2) {
        const float4* sv = &s4[(wid * 64 + lane) * 4];
        float4 a = sv[0], b = sv[1], c = sv[2], d = sv[3];
        E[0] += a.x; E[1] += a.y; E[2] += a.z; E[3] += a.w;
        E[4] += b.x; E[5] += b.y; E[6] += b.z; E[7] += b.w;
        U[0] += c.x; U[1] += c.y; U[2] += c.z; U[3] += c.w;
        U[4] += d.x; U[5] += d.y; U[6] += d.z; U[7] += d.w;
    }
    __syncthreads();
    // Round C: wave 1 dumps, wave 0 adds + stores.
    if (wid == 1) {
        float4* d = &s4[lane * 4];
        d[0] = make_float4(E[0], E[1], E[2], E[3]);
        d[1] = make_float4(E[4], E[5], E[6], E[7]);
        d[2] = make_float4(U[0], U[1], U[2], U[3]);
        d[3] = make_float4(U[4], U[5], U[6], U[7]);
    }
    __syncthreads();
    if (wid == 0) {
        const float4* sv = &s4[lane * 4];
        float4 a = sv[0], b = sv[1], c = sv[2], d = sv[3];
        E[0] += a.x; E[1] += a.y; E[2] += a.z; E[3] += a.w;
        E[4] += b.x; E[5] += b.y; E[6] += b.z; E[7] += b.w;
        U[0] += c.x; U[1] += c.y; U[2] += c.z; U[3] += c.w;
        U[4] += d.x; U[5] += d.y; U[6] += d.z; U[7] += d.w;
        #pragma unroll
        for (int k = 0; k < 8; ++k)
            out[(size_t)(b0 + k) * WL_O + o] = fmaf(-WL_IK, U[k], E[k]);
    }
}

extern "C" void kernel_launch(void* const* d_in, const int* in_sizes, int n_in,
                              void* d_out, int out_size, void* d_ws, size_t ws_size,
                              hipStream_t stream) {
    const float* x           = (const float*)d_in[0];
    const float* translation = (const float*)d_in[1];
    const float* scale_raw   = (const float*)d_in[2];
    const float* weights     = (const float*)d_in[3];
    float*       out         = (float*)d_out;
    P3*          pT3         = (P3*)d_ws;              // 6.3 MB

    wl_prep<<<dim3(WL_O / 64, WL_I / 64), dim3(256), 0, stream>>>(
        translation, scale_raw, weights, pT3);

    wl_main<<<dim3(1024), dim3(512), 0, stream>>>(x, pT3, out);
}

// Round 7
// 114.574 us; speedup vs baseline: 1.4993x; 1.4993x over previous
//
#include <hip/hip_runtime.h>
#include <hip/hip_bf16.h>

// WaveletLinear: y[b,o] = sum_i w[o,i] * (1 - s^2) * exp(-0.5 s^2),
//   s = (x[b,i] - t[o,i]) / (A_MIN + softplus(sr[o,i]) + EPS)
// u = K*s^2, K = 0.5*log2(e); e = exp2(-u); y = sum w*e - (1/K) sum w*(u*e).
//
// R7: R6's 140MB WRITE_SIZE == register spill from __launch_bounds__(512,8)
// (64-VGPR cap vs ~110 needed). Revert to an unstrangled allocator and get
// 8 waves/SIMD via small blocks instead: b-tile 4, 256 thr (4 waves),
// wave = i-quarter x all 4 b. Grid (16 o-slabs, 128 b-tiles) = 2048 blocks
// = 8192 waves; ~56 VGPR -> 8 blocks/CU naturally. 2-D grid keeps R5's
// empirically-validated XCD mapping (bid%8 = gx%8 -> 2 param slabs/XCD L2).

#define WL_A_MIN 0.001f
#define WL_EPS   1e-8f

constexpr int WL_B = 512;
constexpr int WL_O = 1024;
constexpr int WL_I = 512;

#define WL_SQK  0.84932180553704583800f   // sqrt(0.5*log2 e)
#define WL_IK   1.38629436111989061883f   // 1/K = 2 ln 2
#define WL_L2E  1.44269504088896340736f
#define WL_LN2  0.69314718055994530942f

typedef float v2f __attribute__((ext_vector_type(2)));

struct P3 { float nti, inv, w; };          // 12 B

__device__ __forceinline__ float fast_exp2(float a) {
#if __has_builtin(__builtin_amdgcn_exp2f)
    return __builtin_amdgcn_exp2f(a);
#else
    return exp2f(a);
#endif
}
__device__ __forceinline__ float fast_log2(float a) {
#if __has_builtin(__builtin_amdgcn_logf)
    return __builtin_amdgcn_logf(a);
#else
    return __log2f(a);
#endif
}
__device__ __forceinline__ float fast_rcp(float a) {
#if __has_builtin(__builtin_amdgcn_rcpf)
    return __builtin_amdgcn_rcpf(a);
#else
    return 1.0f / a;
#endif
}

__global__ __launch_bounds__(256) void wl_prep(
    const float* __restrict__ translation,
    const float* __restrict__ scale_raw,
    const float* __restrict__ weights,
    P3* __restrict__ pT3)
{
    const int lane   = threadIdx.x & 63;
    const int ic     = threadIdx.x >> 6;               // 0..3
    const int o      = blockIdx.x * 64 + lane;
    const int i_base = blockIdx.y * 64 + ic * 16;

    #pragma unroll 4
    for (int k = 0; k < 16; ++k) {
        int i  = i_base + k;
        int gi = o * WL_I + i;
        float t  = translation[gi];
        float sr = scale_raw[gi];
        float w  = weights[gi];
        float ex    = fast_exp2(sr * WL_L2E);          // softplus via hw exp2/log2
        float sp    = fast_log2(1.0f + ex) * WL_LN2;
        float inv   = fast_rcp(WL_A_MIN + sp + WL_EPS);
        float inv_s = inv * WL_SQK;
        P3 pv; pv.nti = -t * inv_s; pv.inv = inv_s; pv.w = w;
        pT3[(size_t)i * WL_O + o] = pv;
    }
}

// Reduction scratch layout: region per wave w (4 regions), value k (0..7),
// addr = w*544 + k*68 + lane  -> bank (k*4+lane)%32: 2 lanes/bank = free.
constexpr int R_REG = 544;                 // floats per region
constexpr int R_KS  = 68;                  // floats per value-row

__global__ __launch_bounds__(256, 6) void wl_main(
    const float* __restrict__ x,
    const P3* __restrict__ pT3,
    float* __restrict__ out)
{
    __shared__ float smem[4 * R_REG];      // 8704 B; first 8 KB doubles as xT

    const int tid  = threadIdx.x;
    const int lane = tid & 63;
    const int wid  = tid >> 6;             // 0..3 = i-quarter
    const int o    = blockIdx.x * 64 + lane;
    const int b0   = blockIdx.y * 4;

    // ---- stage xT[i*4 + b], i = c*256 + tid: 4 coalesced row loads, one b128 write
    #pragma unroll
    for (int c = 0; c < 2; ++c) {
        int i = c * 256 + tid;
        float4 v;
        v.x = x[(size_t)(b0 + 0) * WL_I + i];
        v.y = x[(size_t)(b0 + 1) * WL_I + i];
        v.z = x[(size_t)(b0 + 2) * WL_I + i];
        v.w = x[(size_t)(b0 + 3) * WL_I + i];
        *reinterpret_cast<float4*>(&smem[i * 4]) = v;
    }
    __syncthreads();

    const P3* pp = pT3 + o;

    v2f aE0 = {0.f, 0.f}, aE1 = {0.f, 0.f};
    v2f aU0 = {0.f, 0.f}, aU1 = {0.f, 0.f};

    const int iBeg = wid * 128;
    #pragma unroll 4
    for (int ii = 0; ii < 128; ++ii) {
        const int i = iBeg + ii;
        P3 p = pp[(size_t)i * WL_O];                       // 768B/wave coalesced
        float4 xq = *reinterpret_cast<const float4*>(&smem[i * 4]);  // uniform b128

        v2f nti = {p.nti, p.nti};
        v2f inv = {p.inv, p.inv};
        v2f wv  = {p.w,  p.w};

        v2f x01 = {xq.x, xq.y};
        v2f x23 = {xq.z, xq.w};

        v2f s0 = __builtin_elementwise_fma(x01, inv, nti);
        v2f s1 = __builtin_elementwise_fma(x23, inv, nti);
        v2f u0 = s0 * s0;
        v2f u1 = s1 * s1;
        v2f e0 = {fast_exp2(-u0.x), fast_exp2(-u0.y)};
        v2f e1 = {fast_exp2(-u1.x), fast_exp2(-u1.y)};
        aE0 = __builtin_elementwise_fma(wv, e0, aE0);
        aE1 = __builtin_elementwise_fma(wv, e1, aE1);
        v2f ue0 = u0 * e0;
        v2f ue1 = u1 * e1;
        aU0 = __builtin_elementwise_fma(wv, ue0, aU0);
        aU1 = __builtin_elementwise_fma(wv, ue1, aU1);
    }

    // ---- cross-wave reduction: every wave dumps 8 scalars, wave 0 combines ----
    __syncthreads();                                       // done reading xT
    {
        float* r = &smem[wid * R_REG + lane];
        r[0 * R_KS] = aE0.x; r[1 * R_KS] = aE0.y;
        r[2 * R_KS] = aE1.x; r[3 * R_KS] = aE1.y;
        r[4 * R_KS] = aU0.x; r[5 * R_KS] = aU0.y;
        r[6 * R_KS] = aU1.x; r[7 * R_KS] = aU1.y;
    }
    __syncthreads();
    if (wid == 0) {
        float E[4] = {0.f, 0.f, 0.f, 0.f};
        float U[4] = {0.f, 0.f, 0.f, 0.f};
        #pragma unroll
        for (int w = 0; w < 4; ++w) {
            const float* r = &smem[w * R_REG + lane];
            E[0] += r[0 * R_KS]; E[1] += r[1 * R_KS];
            E[2] += r[2 * R_KS]; E[3] += r[3 * R_KS];
            U[0] += r[4 * R_KS]; U[1] += r[5 * R_KS];
            U[2] += r[6 * R_KS]; U[3] += r[7 * R_KS];
        }
        #pragma unroll
        for (int k = 0; k < 4; ++k)
            out[(size_t)(b0 + k) * WL_O + o] = fmaf(-WL_IK, U[k], E[k]);
    }
}

extern "C" void kernel_launch(void* const* d_in, const int* in_sizes, int n_in,
                              void* d_out, int out_size, void* d_ws, size_t ws_size,
                              hipStream_t stream) {
    const float* x           = (const float*)d_in[0];
    const float* translation = (const float*)d_in[1];
    const float* scale_raw   = (const float*)d_in[2];
    const float* weights     = (const float*)d_in[3];
    float*       out         = (float*)d_out;
    P3*          pT3         = (P3*)d_ws;              // 6.3 MB

    wl_prep<<<dim3(WL_O / 64, WL_I / 64), dim3(256), 0, stream>>>(
        translation, scale_raw, weights, pT3);

    // grid (o-slabs, b-tiles): bid%8 = gx%8 -> XCD k caches slabs {k, k+8}.
    wl_main<<<dim3(WL_O / 64, WL_B / 4), dim3(256), 0, stream>>>(x, pT3, out);
}